// Round 1
// baseline (2983.390 us; speedup 1.0000x reference)
//
#include <hip/hip_runtime.h>
#include <hip/hip_bf16.h>
#include <math.h>

#define F 128
#define PN_EPS 1e-5f
#define PN_SCALE 1.0f
#define GR 32  // rows per block in GEMM

__device__ __forceinline__ void atomic_add_f32(float* p, float v) {
#if defined(__AMDGCN__)
    unsafeAtomicAdd(p, v);   // global_atomic_add_f32 (no CAS loop); denorm-flush irrelevant here
#else
    atomicAdd(p, v);
#endif
}

// K0: deg=1.0 (self-loop weight), zero stats accumulators
__global__ void init_kernel(float* __restrict__ deg, float* __restrict__ colsum,
                            float* __restrict__ sumsq, int n) {
    int i = blockIdx.x * blockDim.x + threadIdx.x;
    if (i < n) deg[i] = 1.0f;
    if (i < F) colsum[i] = 0.0f;
    if (i == F) sumsq[0] = 0.0f;
}

// K1: deg[dst] += w
__global__ void edge_deg(const int* __restrict__ dst, const float* __restrict__ ew,
                         float* __restrict__ deg, int E) {
    int i = blockIdx.x * blockDim.x + threadIdx.x;
    int stride = gridDim.x * blockDim.x;
    for (int e = i; e < E; e += stride)
        atomic_add_f32(&deg[dst[e]], ew[e]);
}

// K2: dis = deg>0 ? rsqrt(deg) : 0   (in place)
__global__ void make_dis(float* __restrict__ deg, int n) {
    int i = blockIdx.x * blockDim.x + threadIdx.x;
    if (i < n) {
        float d = deg[i];
        deg[i] = (d > 0.0f) ? rsqrtf(d) : 0.0f;
    }
}

// K3: h = x @ W  (f32 vector GEMM), epilogue writes h and agg0 = h*dis^2 + bias
// 128 threads: thread owns column `col`; 32 rows staged in LDS; W column chunk in regs.
__global__ __launch_bounds__(128) void gemm_agg0(
    const float* __restrict__ x, const float* __restrict__ W,
    const float* __restrict__ bias, const float* __restrict__ dis,
    float* __restrict__ h, float* __restrict__ agg, int n) {
    __shared__ float xs[GR][F];
    const int col = threadIdx.x;
    const int row0 = blockIdx.x * GR;
    const int rows = min(GR, n - row0);

    for (int idx = threadIdx.x; idx < rows * (F / 4); idx += blockDim.x) {
        int r = idx >> 5;          // F/4 == 32
        int c = idx & 31;
        ((float4*)&xs[r][0])[c] = ((const float4*)(x + (size_t)(row0 + r) * F))[c];
    }
    __syncthreads();

    float acc[GR];
#pragma unroll
    for (int r = 0; r < GR; ++r) acc[r] = 0.0f;

    for (int kc = 0; kc < F; kc += 32) {
        float wreg[32];
#pragma unroll
        for (int kk = 0; kk < 32; ++kk) wreg[kk] = W[(size_t)(kc + kk) * F + col];
#pragma unroll
        for (int r = 0; r < GR; ++r) {
            float a = acc[r];
#pragma unroll
            for (int kk = 0; kk < 32; ++kk) a = fmaf(xs[r][kc + kk], wreg[kk], a);
            acc[r] = a;
        }
    }

    float bv = bias[col];
#pragma unroll
    for (int r = 0; r < GR; ++r) {
        if (r < rows) {
            float dv = dis[row0 + r];
            size_t o = (size_t)(row0 + r) * F + col;
            h[o] = acc[r];
            agg[o] = fmaf(acc[r], dv * dv, bv);
        }
    }
}

// K4: agg[dst] += h[src] * (dis[src]*w*dis[dst]); 32 lanes per edge, float4 per lane
__global__ __launch_bounds__(256) void edge_agg(
    const int* __restrict__ src, const int* __restrict__ dst,
    const float* __restrict__ ew, const float* __restrict__ dis,
    const float* __restrict__ h, float* __restrict__ agg, int E) {
    const int lane = threadIdx.x & 31;
    int grp = (blockIdx.x * blockDim.x + threadIdx.x) >> 5;
    const int nGrp = (gridDim.x * blockDim.x) >> 5;
    for (int e = grp; e < E; e += nGrp) {
        int s = src[e];
        int d = dst[e];
        float nrm = dis[s] * ew[e] * dis[d];
        float4 v = ((const float4*)(h + (size_t)s * F))[lane];
        float* o = agg + (size_t)d * F + lane * 4;
        atomic_add_f32(o + 0, v.x * nrm);
        atomic_add_f32(o + 1, v.y * nrm);
        atomic_add_f32(o + 2, v.z * nrm);
        atomic_add_f32(o + 3, v.w * nrm);
    }
}

// K5: column sums + total sum of squares
__global__ __launch_bounds__(256) void stats(const float* __restrict__ agg,
                                             float* __restrict__ colsum,
                                             float* __restrict__ sumsq, int n) {
    const int col = threadIdx.x & (F - 1);
    const int plane = threadIdx.x >> 7;  // 0 or 1
    float cs = 0.0f, ss = 0.0f;
    for (int r = blockIdx.x * 2 + plane; r < n; r += gridDim.x * 2) {
        float v = agg[(size_t)r * F + col];
        cs += v;
        ss = fmaf(v, v, ss);
    }
    __shared__ float scs[256];
    scs[threadIdx.x] = cs;
    __syncthreads();
    if (threadIdx.x < F)
        atomic_add_f32(&colsum[threadIdx.x], scs[threadIdx.x] + scs[threadIdx.x + F]);

#pragma unroll
    for (int off = 32; off >= 1; off >>= 1) ss += __shfl_down(ss, off);
    __shared__ float sss[4];
    if ((threadIdx.x & 63) == 0) sss[threadIdx.x >> 6] = ss;
    __syncthreads();
    if (threadIdx.x == 0) atomic_add_f32(sumsq, sss[0] + sss[1] + sss[2] + sss[3]);
}

// K5.5: mean[f] = colsum[f]/n ; invd = scale / sqrt(eps + (sumsq - n*sum(mean^2))/n)
__global__ void reduce_stats(const float* __restrict__ colsum, const float* __restrict__ sumsq,
                             float* __restrict__ mean, float* __restrict__ invd, int n) {
    int t = threadIdx.x;  // 128 threads
    float m = colsum[t] / (float)n;
    mean[t] = m;
    __shared__ float red[128];
    red[t] = m * m;
    __syncthreads();
    for (int off = 64; off >= 1; off >>= 1) {
        if (t < off) red[t] += red[t + off];
        __syncthreads();
    }
    if (t == 0) {
        float ssc = sumsq[0] - (float)n * red[0];
        if (ssc < 0.0f) ssc = 0.0f;
        float denom = sqrtf(PN_EPS + ssc / (float)n);
        invd[0] = PN_SCALE / denom;
    }
}

// K6: out = relu((agg - mean) * invd)   in place on d_out
__global__ __launch_bounds__(256) void finalize(float* __restrict__ out,
                                                const float* __restrict__ mean,
                                                const float* __restrict__ invd, int n) {
    __shared__ float sm[F];
    __shared__ float siv;
    if (threadIdx.x < F) sm[threadIdx.x] = mean[threadIdx.x];
    if (threadIdx.x == 0) siv = invd[0];
    __syncthreads();
    float iv = siv;
    size_t total = (size_t)n * (F / 4);
    size_t i0 = (size_t)blockIdx.x * blockDim.x + threadIdx.x;
    size_t stride = (size_t)gridDim.x * blockDim.x;
    float4* o4 = (float4*)out;
    for (size_t i = i0; i < total; i += stride) {
        int c = (int)((i & 31) << 2);  // (i % (F/4)) * 4
        float4 v = o4[i];
        v.x = fmaxf(0.0f, (v.x - sm[c + 0]) * iv);
        v.y = fmaxf(0.0f, (v.y - sm[c + 1]) * iv);
        v.z = fmaxf(0.0f, (v.z - sm[c + 2]) * iv);
        v.w = fmaxf(0.0f, (v.w - sm[c + 3]) * iv);
        o4[i] = v;
    }
}

extern "C" void kernel_launch(void* const* d_in, const int* in_sizes, int n_in,
                              void* d_out, int out_size, void* d_ws, size_t ws_size,
                              hipStream_t stream) {
    const float* x    = (const float*)d_in[0];
    const int*   ei   = (const int*)d_in[1];   // [2, E] int32 (harness converts integer -> int)
    const float* ew   = (const float*)d_in[2];
    const float* W    = (const float*)d_in[3];
    const float* bias = (const float*)d_in[4];
    float* out = (float*)d_out;

    const int n = in_sizes[0] / F;
    const int E = in_sizes[2];
    const int* src = ei;
    const int* dst = ei + E;

    char* ws = (char*)d_ws;
    float* h      = (float*)ws;                       // n*F floats
    float* deg    = (float*)(ws + (size_t)n * F * 4); // n floats (becomes dis in place)
    float* colsum = deg + n;                          // F
    float* sumsq  = colsum + F;                       // 1
    float* mean   = sumsq + 1;                        // F
    float* invd   = mean + F;                         // 1

    init_kernel<<<(n + 255) / 256, 256, 0, stream>>>(deg, colsum, sumsq, n);
    edge_deg<<<1024, 256, 0, stream>>>(dst, ew, deg, E);
    make_dis<<<(n + 255) / 256, 256, 0, stream>>>(deg, n);
    gemm_agg0<<<(n + GR - 1) / GR, 128, 0, stream>>>(x, W, bias, deg, h, out, n);
    edge_agg<<<4096, 256, 0, stream>>>(src, dst, ew, deg, h, out, E);
    stats<<<2048, 256, 0, stream>>>(out, colsum, sumsq, n);
    reduce_stats<<<1, 128, 0, stream>>>(colsum, sumsq, mean, invd, n);
    finalize<<<2048, 256, 0, stream>>>(out, mean, invd, n);
}

// Round 2
// 546.650 us; speedup vs baseline: 5.4576x; 5.4576x over previous
//
#include <hip/hip_runtime.h>
#include <hip/hip_bf16.h>
#include <math.h>

#define F 128
#define PN_EPS 1e-5f
#define PN_SCALE 1.0f
#define GR 32   // rows per block in GEMM
#define SCAN_CHUNK 1024  // elements per scan block (256 thr * 4)

__device__ __forceinline__ void atomic_add_f32(float* p, float v) {
#if defined(__AMDGCN__)
    unsafeAtomicAdd(p, v);   // global_atomic_add_f32, no CAS loop
#else
    atomicAdd(p, v);
#endif
}

// K0: deg=1.0 (self-loop weight), cnt=0, zero stats accumulators
__global__ void init_kernel(float* __restrict__ deg, int* __restrict__ cnt,
                            float* __restrict__ colsum, float* __restrict__ sumsq, int n) {
    int i = blockIdx.x * blockDim.x + threadIdx.x;
    if (i < n) { deg[i] = 1.0f; cnt[i] = 0; }
    if (i < F) colsum[i] = 0.0f;
    if (i == F) sumsq[0] = 0.0f;
}

// K1: deg[dst] += w ; cnt[dst]++   (fused histogram)
__global__ void edge_deg_hist(const int* __restrict__ dst, const float* __restrict__ ew,
                              float* __restrict__ deg, int* __restrict__ cnt, int E) {
    int i = blockIdx.x * blockDim.x + threadIdx.x;
    int stride = gridDim.x * blockDim.x;
    for (int e = i; e < E; e += stride) {
        int d = dst[e];
        atomic_add_f32(&deg[d], ew[e]);
        atomicAdd(&cnt[d], 1);
    }
}

// K2: dis = deg>0 ? rsqrt(deg) : 0   (in place)
__global__ void make_dis(float* __restrict__ deg, int n) {
    int i = blockIdx.x * blockDim.x + threadIdx.x;
    if (i < n) {
        float d = deg[i];
        deg[i] = (d > 0.0f) ? rsqrtf(d) : 0.0f;
    }
}

// --- 3-kernel exclusive scan of cnt[n] -> row_start[n] (and cursor[n] copy) ---
__global__ __launch_bounds__(256) void scan_pass1(const int* __restrict__ cnt,
                                                  int* __restrict__ bsum, int n) {
    __shared__ int s[256];
    int base = blockIdx.x * SCAN_CHUNK + threadIdx.x * 4;
    int t = 0;
#pragma unroll
    for (int k = 0; k < 4; ++k)
        if (base + k < n) t += cnt[base + k];
    s[threadIdx.x] = t;
    __syncthreads();
    for (int off = 128; off >= 1; off >>= 1) {
        if (threadIdx.x < off) s[threadIdx.x] += s[threadIdx.x + off];
        __syncthreads();
    }
    if (threadIdx.x == 0) bsum[blockIdx.x] = s[0];
}

// single block, exclusive scan of nb (<=256) block sums in place
__global__ __launch_bounds__(256) void scan_pass2(int* __restrict__ bsum, int nb) {
    __shared__ int s[256];
    int t = threadIdx.x;
    int v = (t < nb) ? bsum[t] : 0;
    s[t] = v;
    __syncthreads();
    for (int off = 1; off < 256; off <<= 1) {
        int u = (t >= off) ? s[t - off] : 0;
        __syncthreads();
        s[t] += u;
        __syncthreads();
    }
    if (t < nb) bsum[t] = s[t] - v;  // exclusive
}

__global__ __launch_bounds__(256) void scan_pass3(const int* __restrict__ cnt,
                                                  const int* __restrict__ bsum,
                                                  int* __restrict__ row_start,
                                                  int* __restrict__ cursor, int n) {
    __shared__ int s[256];
    int base = blockIdx.x * SCAN_CHUNK + threadIdx.x * 4;
    int c[4];
    int tot = 0;
#pragma unroll
    for (int k = 0; k < 4; ++k) {
        c[k] = (base + k < n) ? cnt[base + k] : 0;
        tot += c[k];
    }
    s[threadIdx.x] = tot;
    __syncthreads();
    for (int off = 1; off < 256; off <<= 1) {
        int u = (threadIdx.x >= off) ? s[threadIdx.x - off] : 0;
        __syncthreads();
        s[threadIdx.x] += u;
        __syncthreads();
    }
    int off = bsum[blockIdx.x] + s[threadIdx.x] - tot;  // exclusive within grid
#pragma unroll
    for (int k = 0; k < 4; ++k) {
        if (base + k < n) {
            row_start[base + k] = off;
            cursor[base + k] = off;
            off += c[k];
        }
    }
}

// K3: scatter edges into CSR rows: csr[pos] = {src, norm}
__global__ __launch_bounds__(256) void scatter(const int* __restrict__ src,
                                               const int* __restrict__ dst,
                                               const float* __restrict__ ew,
                                               const float* __restrict__ dis,
                                               int* __restrict__ cursor,
                                               uint2* __restrict__ csr, int E) {
    int i = blockIdx.x * blockDim.x + threadIdx.x;
    int stride = gridDim.x * blockDim.x;
    for (int e = i; e < E; e += stride) {
        int s = src[e];
        int d = dst[e];
        float nrm = dis[s] * ew[e] * dis[d];
        int pos = atomicAdd(&cursor[d], 1);
        csr[pos] = make_uint2((unsigned)s, __float_as_uint(nrm));
    }
}

// K4: h = x @ W  (f32 vector GEMM)
__global__ __launch_bounds__(128) void gemm(
    const float* __restrict__ x, const float* __restrict__ W,
    float* __restrict__ h, int n) {
    __shared__ float xs[GR][F];
    const int col = threadIdx.x;
    const int row0 = blockIdx.x * GR;
    const int rows = min(GR, n - row0);

    for (int idx = threadIdx.x; idx < rows * (F / 4); idx += blockDim.x) {
        int r = idx >> 5;
        int c = idx & 31;
        ((float4*)&xs[r][0])[c] = ((const float4*)(x + (size_t)(row0 + r) * F))[c];
    }
    __syncthreads();

    float acc[GR];
#pragma unroll
    for (int r = 0; r < GR; ++r) acc[r] = 0.0f;

    for (int kc = 0; kc < F; kc += 32) {
        float wreg[32];
#pragma unroll
        for (int kk = 0; kk < 32; ++kk) wreg[kk] = W[(size_t)(kc + kk) * F + col];
#pragma unroll
        for (int r = 0; r < GR; ++r) {
            float a = acc[r];
#pragma unroll
            for (int kk = 0; kk < 32; ++kk) a = fmaf(xs[r][kc + kk], wreg[kk], a);
            acc[r] = a;
        }
    }

#pragma unroll
    for (int r = 0; r < GR; ++r)
        if (r < rows) h[(size_t)(row0 + r) * F + col] = acc[r];
}

// K5: atomic-free aggregation. One 32-lane group per dst node.
// acc = h[i]*dis[i]^2 + bias  +  sum_{e in row(i)} h[src_e] * norm_e
__global__ __launch_bounds__(256) void aggregate(
    const float4* __restrict__ h4, const float* __restrict__ dis,
    const float4* __restrict__ bias4,
    const int* __restrict__ row_start, const int* __restrict__ row_end,
    const uint2* __restrict__ csr, float4* __restrict__ out4, int n) {
    int g = (blockIdx.x * blockDim.x + threadIdx.x) >> 5;
    int lane = threadIdx.x & 31;
    if (g >= n) return;

    float dv = dis[g];
    float sc = dv * dv;
    float4 b = bias4[lane];
    float4 hv = h4[(size_t)g * 32 + lane];
    float4 acc;
    acc.x = fmaf(hv.x, sc, b.x);
    acc.y = fmaf(hv.y, sc, b.y);
    acc.z = fmaf(hv.z, sc, b.z);
    acc.w = fmaf(hv.w, sc, b.w);

    int e = row_start[g];
    const int e1 = row_end[g];
    for (; e + 1 < e1; e += 2) {
        uint2 r0 = csr[e];
        uint2 r1 = csr[e + 1];
        float n0 = __uint_as_float(r0.y);
        float n1 = __uint_as_float(r1.y);
        float4 v0 = h4[(size_t)r0.x * 32 + lane];
        float4 v1 = h4[(size_t)r1.x * 32 + lane];
        acc.x = fmaf(v0.x, n0, acc.x); acc.y = fmaf(v0.y, n0, acc.y);
        acc.z = fmaf(v0.z, n0, acc.z); acc.w = fmaf(v0.w, n0, acc.w);
        acc.x = fmaf(v1.x, n1, acc.x); acc.y = fmaf(v1.y, n1, acc.y);
        acc.z = fmaf(v1.z, n1, acc.z); acc.w = fmaf(v1.w, n1, acc.w);
    }
    if (e < e1) {
        uint2 r0 = csr[e];
        float n0 = __uint_as_float(r0.y);
        float4 v0 = h4[(size_t)r0.x * 32 + lane];
        acc.x = fmaf(v0.x, n0, acc.x); acc.y = fmaf(v0.y, n0, acc.y);
        acc.z = fmaf(v0.z, n0, acc.z); acc.w = fmaf(v0.w, n0, acc.w);
    }
    out4[(size_t)g * 32 + lane] = acc;
}

// K6: column sums + total sum of squares
__global__ __launch_bounds__(256) void stats(const float* __restrict__ agg,
                                             float* __restrict__ colsum,
                                             float* __restrict__ sumsq, int n) {
    const int col = threadIdx.x & (F - 1);
    const int plane = threadIdx.x >> 7;
    float cs = 0.0f, ss = 0.0f;
    for (int r = blockIdx.x * 2 + plane; r < n; r += gridDim.x * 2) {
        float v = agg[(size_t)r * F + col];
        cs += v;
        ss = fmaf(v, v, ss);
    }
    __shared__ float scs[256];
    scs[threadIdx.x] = cs;
    __syncthreads();
    if (threadIdx.x < F)
        atomic_add_f32(&colsum[threadIdx.x], scs[threadIdx.x] + scs[threadIdx.x + F]);

#pragma unroll
    for (int off = 32; off >= 1; off >>= 1) ss += __shfl_down(ss, off);
    __shared__ float sss[4];
    if ((threadIdx.x & 63) == 0) sss[threadIdx.x >> 6] = ss;
    __syncthreads();
    if (threadIdx.x == 0) atomic_add_f32(sumsq, sss[0] + sss[1] + sss[2] + sss[3]);
}

// K7: mean + inverse denom
__global__ void reduce_stats(const float* __restrict__ colsum, const float* __restrict__ sumsq,
                             float* __restrict__ mean, float* __restrict__ invd, int n) {
    int t = threadIdx.x;  // 128 threads
    float m = colsum[t] / (float)n;
    mean[t] = m;
    __shared__ float red[128];
    red[t] = m * m;
    __syncthreads();
    for (int off = 64; off >= 1; off >>= 1) {
        if (t < off) red[t] += red[t + off];
        __syncthreads();
    }
    if (t == 0) {
        float ssc = sumsq[0] - (float)n * red[0];
        if (ssc < 0.0f) ssc = 0.0f;
        float denom = sqrtf(PN_EPS + ssc / (float)n);
        invd[0] = PN_SCALE / denom;
    }
}

// K8: out = relu((out - mean) * invd)   in place
__global__ __launch_bounds__(256) void finalize(float* __restrict__ out,
                                                const float* __restrict__ mean,
                                                const float* __restrict__ invd, int n) {
    __shared__ float sm[F];
    __shared__ float siv;
    if (threadIdx.x < F) sm[threadIdx.x] = mean[threadIdx.x];
    if (threadIdx.x == 0) siv = invd[0];
    __syncthreads();
    float iv = siv;
    size_t total = (size_t)n * (F / 4);
    size_t i0 = (size_t)blockIdx.x * blockDim.x + threadIdx.x;
    size_t stride = (size_t)gridDim.x * blockDim.x;
    float4* o4 = (float4*)out;
    for (size_t i = i0; i < total; i += stride) {
        int c = (int)((i & 31) << 2);
        float4 v = o4[i];
        v.x = fmaxf(0.0f, (v.x - sm[c + 0]) * iv);
        v.y = fmaxf(0.0f, (v.y - sm[c + 1]) * iv);
        v.z = fmaxf(0.0f, (v.z - sm[c + 2]) * iv);
        v.w = fmaxf(0.0f, (v.w - sm[c + 3]) * iv);
        o4[i] = v;
    }
}

extern "C" void kernel_launch(void* const* d_in, const int* in_sizes, int n_in,
                              void* d_out, int out_size, void* d_ws, size_t ws_size,
                              hipStream_t stream) {
    const float* x    = (const float*)d_in[0];
    const int*   ei   = (const int*)d_in[1];   // [2, E] int32
    const float* ew   = (const float*)d_in[2];
    const float* W    = (const float*)d_in[3];
    const float* bias = (const float*)d_in[4];
    float* out = (float*)d_out;

    const int n = in_sizes[0] / F;
    const int E = in_sizes[2];
    const int* src = ei;
    const int* dst = ei + E;

    char* ws = (char*)d_ws;
    size_t off = 0;
    float* h = (float*)(ws + off);        off += (size_t)n * F * sizeof(float);
    uint2* csr = (uint2*)(ws + off);      off += (size_t)E * sizeof(uint2);
    float* deg = (float*)(ws + off);      off += (size_t)n * sizeof(float);
    int* row_start = (int*)(ws + off);    off += (size_t)n * sizeof(int);
    int* cursor = (int*)(ws + off);       off += (size_t)n * sizeof(int);
    int* bsum = (int*)(ws + off);         off += 256 * sizeof(int);
    float* colsum = (float*)(ws + off);   off += F * sizeof(float);
    float* sumsq = (float*)(ws + off);    off += sizeof(float);
    float* mean = (float*)(ws + off);     off += F * sizeof(float);
    float* invd = (float*)(ws + off);     off += sizeof(float);

    const int nb = (n + SCAN_CHUNK - 1) / SCAN_CHUNK;  // <=256 for n<=262144

    init_kernel<<<(n + 255) / 256, 256, 0, stream>>>(deg, cursor /*as cnt*/, colsum, sumsq, n);
    edge_deg_hist<<<2048, 256, 0, stream>>>(dst, ew, deg, cursor, E);
    make_dis<<<(n + 255) / 256, 256, 0, stream>>>(deg, n);
    scan_pass1<<<nb, 256, 0, stream>>>(cursor, bsum, n);
    scan_pass2<<<1, 256, 0, stream>>>(bsum, nb);
    scan_pass3<<<nb, 256, 0, stream>>>(cursor, bsum, row_start, cursor, n);
    scatter<<<2048, 256, 0, stream>>>(src, dst, ew, deg, cursor, csr, E);
    gemm<<<(n + GR - 1) / GR, 128, 0, stream>>>(x, W, h, n);
    aggregate<<<(n * 32 + 255) / 256, 256, 0, stream>>>(
        (const float4*)h, deg, (const float4*)bias, row_start, cursor /*row_end*/,
        csr, (float4*)out, n);
    stats<<<2048, 256, 0, stream>>>(out, colsum, sumsq, n);
    reduce_stats<<<1, 128, 0, stream>>>(colsum, sumsq, mean, invd, n);
    finalize<<<2048, 256, 0, stream>>>(out, mean, invd, n);
}

// Round 3
// 380.349 us; speedup vs baseline: 7.8438x; 1.4372x over previous
//
#include <hip/hip_runtime.h>
#include <hip/hip_bf16.h>
#include <math.h>

#define F 128
#define PN_EPS 1e-5f
#define PN_SCALE 1.0f
#define GR 32            // rows per block in GEMM
#define SCAN_CHUNK 1024  // elements per scan block (256 thr * 4)
#define FIX_SCALE 16777216.0f       // 2^24
#define FIX_INV   (1.0f / 16777216.0f)

__device__ __forceinline__ void atomic_add_f32(float* p, float v) {
#if defined(__AMDGCN__)
    unsafeAtomicAdd(p, v);
#else
    atomicAdd(p, v);
#endif
}

// K0: packed=0, zero stats accumulators
__global__ void init_kernel(unsigned long long* __restrict__ packed,
                            float* __restrict__ colsum, float* __restrict__ sumsq, int n) {
    int i = blockIdx.x * blockDim.x + threadIdx.x;
    if (i < n) packed[i] = 0ull;
    if (i < F) colsum[i] = 0.0f;
    if (i == F) sumsq[0] = 0.0f;
}

// K1: one u64 atomic per edge: packed[dst] += (1<<40) | fix24(w).
// Return value's high bits give this edge's rank within its dst bucket.
__global__ __launch_bounds__(256) void edge_hist(
    const int* __restrict__ dst, const float* __restrict__ ew,
    unsigned long long* __restrict__ packed, unsigned short* __restrict__ rank, int E) {
    int i = blockIdx.x * blockDim.x + threadIdx.x;
    int stride = gridDim.x * blockDim.x;
    for (int e = i; e < E; e += stride) {
        int d = dst[e];
        unsigned long long add =
            (1ull << 40) | (unsigned long long)__float2uint_rn(ew[e] * FIX_SCALE);
        unsigned long long old = atomicAdd(&packed[d], add);
        rank[e] = (unsigned short)(old >> 40);
    }
}

// K2: unpack -> cnt (for scan) and dis = rsqrt(1 + sum_w)
__global__ void unpack(const unsigned long long* __restrict__ packed,
                       int* __restrict__ cnt, float* __restrict__ dis, int n) {
    int i = blockIdx.x * blockDim.x + threadIdx.x;
    if (i < n) {
        unsigned long long p = packed[i];
        cnt[i] = (int)(p >> 40);
        float deg = 1.0f + (float)(p & ((1ull << 40) - 1)) * FIX_INV;
        dis[i] = rsqrtf(deg);
    }
}

// --- 3-kernel exclusive scan of cnt[n] -> row_start[n] ---
__global__ __launch_bounds__(256) void scan_pass1(const int* __restrict__ cnt,
                                                  int* __restrict__ bsum, int n) {
    __shared__ int s[256];
    int base = blockIdx.x * SCAN_CHUNK + threadIdx.x * 4;
    int t = 0;
#pragma unroll
    for (int k = 0; k < 4; ++k)
        if (base + k < n) t += cnt[base + k];
    s[threadIdx.x] = t;
    __syncthreads();
    for (int off = 128; off >= 1; off >>= 1) {
        if (threadIdx.x < off) s[threadIdx.x] += s[threadIdx.x + off];
        __syncthreads();
    }
    if (threadIdx.x == 0) bsum[blockIdx.x] = s[0];
}

__global__ __launch_bounds__(256) void scan_pass2(int* __restrict__ bsum, int nb) {
    __shared__ int s[256];
    int t = threadIdx.x;
    int v = (t < nb) ? bsum[t] : 0;
    s[t] = v;
    __syncthreads();
    for (int off = 1; off < 256; off <<= 1) {
        int u = (t >= off) ? s[t - off] : 0;
        __syncthreads();
        s[t] += u;
        __syncthreads();
    }
    if (t < nb) bsum[t] = s[t] - v;  // exclusive
}

__global__ __launch_bounds__(256) void scan_pass3(const int* __restrict__ cnt,
                                                  const int* __restrict__ bsum,
                                                  int* __restrict__ row_start, int n) {
    __shared__ int s[256];
    int base = blockIdx.x * SCAN_CHUNK + threadIdx.x * 4;
    int c[4];
    int tot = 0;
#pragma unroll
    for (int k = 0; k < 4; ++k) {
        c[k] = (base + k < n) ? cnt[base + k] : 0;
        tot += c[k];
    }
    s[threadIdx.x] = tot;
    __syncthreads();
    for (int off = 1; off < 256; off <<= 1) {
        int u = (threadIdx.x >= off) ? s[threadIdx.x - off] : 0;
        __syncthreads();
        s[threadIdx.x] += u;
        __syncthreads();
    }
    int off = bsum[blockIdx.x] + s[threadIdx.x] - tot;
#pragma unroll
    for (int k = 0; k < 4; ++k) {
        if (base + k < n) {
            row_start[base + k] = off;
            off += c[k];
        }
    }
}

// K3: atomic-free scatter: csr[row_start[dst]+rank] = {src, norm}
__global__ __launch_bounds__(256) void scatter(const int* __restrict__ src,
                                               const int* __restrict__ dst,
                                               const float* __restrict__ ew,
                                               const unsigned short* __restrict__ rank,
                                               const float* __restrict__ dis,
                                               const int* __restrict__ row_start,
                                               uint2* __restrict__ csr, int E) {
    int i = blockIdx.x * blockDim.x + threadIdx.x;
    int stride = gridDim.x * blockDim.x;
    for (int e = i; e < E; e += stride) {
        int s = src[e];
        int d = dst[e];
        float nrm = dis[s] * ew[e] * dis[d];
        int pos = row_start[d] + (int)rank[e];
        csr[pos] = make_uint2((unsigned)s, __float_as_uint(nrm));
    }
}

// K4: h = x @ W  (f32 vector GEMM), bf16 output
__global__ __launch_bounds__(128) void gemm(
    const float* __restrict__ x, const float* __restrict__ W,
    __hip_bfloat16* __restrict__ h, int n) {
    __shared__ float xs[GR][F];
    const int col = threadIdx.x;
    const int row0 = blockIdx.x * GR;
    const int rows = min(GR, n - row0);

    for (int idx = threadIdx.x; idx < rows * (F / 4); idx += blockDim.x) {
        int r = idx >> 5;
        int c = idx & 31;
        ((float4*)&xs[r][0])[c] = ((const float4*)(x + (size_t)(row0 + r) * F))[c];
    }
    __syncthreads();

    float acc[GR];
#pragma unroll
    for (int r = 0; r < GR; ++r) acc[r] = 0.0f;

    for (int kc = 0; kc < F; kc += 32) {
        float wreg[32];
#pragma unroll
        for (int kk = 0; kk < 32; ++kk) wreg[kk] = W[(size_t)(kc + kk) * F + col];
#pragma unroll
        for (int r = 0; r < GR; ++r) {
            float a = acc[r];
#pragma unroll
            for (int kk = 0; kk < 32; ++kk) a = fmaf(xs[r][kc + kk], wreg[kk], a);
            acc[r] = a;
        }
    }

#pragma unroll
    for (int r = 0; r < GR; ++r)
        if (r < rows) h[(size_t)(row0 + r) * F + col] = __float2bfloat16(acc[r]);
}

// K5: atomic-free aggregation, 16 lanes per dst node, bf16 h gathers.
// acc = h[i]*dis[i]^2 + bias  +  sum_{e in row(i)} h[src_e] * norm_e
__device__ __forceinline__ void bf16x8_fma(uint4 v, float m, float* acc) {
    union { uint4 u; unsigned short s[8]; } cv;
    cv.u = v;
#pragma unroll
    for (int j = 0; j < 8; ++j) {
        float f = __uint_as_float(((unsigned)cv.s[j]) << 16);
        acc[j] = fmaf(f, m, acc[j]);
    }
}

__global__ __launch_bounds__(256) void aggregate(
    const uint4* __restrict__ h16,   // node row = 16 chunks of 8 bf16
    const float* __restrict__ dis,
    const float* __restrict__ bias,
    const int* __restrict__ row_start, const int* __restrict__ cnt,
    const uint2* __restrict__ csr, float4* __restrict__ out4, int n) {
    int g = (blockIdx.x * blockDim.x + threadIdx.x) >> 4;
    int lane = threadIdx.x & 15;
    if (g >= n) return;

    float dv = dis[g];
    float sc = dv * dv;
    float4 b0 = ((const float4*)bias)[lane * 2];
    float4 b1 = ((const float4*)bias)[lane * 2 + 1];
    float acc[8] = {b0.x, b0.y, b0.z, b0.w, b1.x, b1.y, b1.z, b1.w};
    bf16x8_fma(h16[(size_t)g * 16 + lane], sc, acc);

    int e = row_start[g];
    const int e1 = e + cnt[g];
    for (; e + 1 < e1; e += 2) {
        uint2 r0 = csr[e];
        uint2 r1 = csr[e + 1];
        uint4 v0 = h16[(size_t)r0.x * 16 + lane];
        uint4 v1 = h16[(size_t)r1.x * 16 + lane];
        bf16x8_fma(v0, __uint_as_float(r0.y), acc);
        bf16x8_fma(v1, __uint_as_float(r1.y), acc);
    }
    if (e < e1) {
        uint2 r0 = csr[e];
        bf16x8_fma(h16[(size_t)r0.x * 16 + lane], __uint_as_float(r0.y), acc);
    }

    out4[(size_t)g * 32 + lane * 2]     = make_float4(acc[0], acc[1], acc[2], acc[3]);
    out4[(size_t)g * 32 + lane * 2 + 1] = make_float4(acc[4], acc[5], acc[6], acc[7]);
}

// K6: column sums + total sum of squares
__global__ __launch_bounds__(256) void stats(const float* __restrict__ agg,
                                             float* __restrict__ colsum,
                                             float* __restrict__ sumsq, int n) {
    const int col = threadIdx.x & (F - 1);
    const int plane = threadIdx.x >> 7;
    float cs = 0.0f, ss = 0.0f;
    for (int r = blockIdx.x * 2 + plane; r < n; r += gridDim.x * 2) {
        float v = agg[(size_t)r * F + col];
        cs += v;
        ss = fmaf(v, v, ss);
    }
    __shared__ float scs[256];
    scs[threadIdx.x] = cs;
    __syncthreads();
    if (threadIdx.x < F)
        atomic_add_f32(&colsum[threadIdx.x], scs[threadIdx.x] + scs[threadIdx.x + F]);

#pragma unroll
    for (int off = 32; off >= 1; off >>= 1) ss += __shfl_down(ss, off);
    __shared__ float sss[4];
    if ((threadIdx.x & 63) == 0) sss[threadIdx.x >> 6] = ss;
    __syncthreads();
    if (threadIdx.x == 0) atomic_add_f32(sumsq, sss[0] + sss[1] + sss[2] + sss[3]);
}

// K7: mean + inverse denom
__global__ void reduce_stats(const float* __restrict__ colsum, const float* __restrict__ sumsq,
                             float* __restrict__ mean, float* __restrict__ invd, int n) {
    int t = threadIdx.x;  // 128 threads
    float m = colsum[t] / (float)n;
    mean[t] = m;
    __shared__ float red[128];
    red[t] = m * m;
    __syncthreads();
    for (int off = 64; off >= 1; off >>= 1) {
        if (t < off) red[t] += red[t + off];
        __syncthreads();
    }
    if (t == 0) {
        float ssc = sumsq[0] - (float)n * red[0];
        if (ssc < 0.0f) ssc = 0.0f;
        float denom = sqrtf(PN_EPS + ssc / (float)n);
        invd[0] = PN_SCALE / denom;
    }
}

// K8: out = relu((out - mean) * invd)   in place
__global__ __launch_bounds__(256) void finalize(float* __restrict__ out,
                                                const float* __restrict__ mean,
                                                const float* __restrict__ invd, int n) {
    __shared__ float sm[F];
    __shared__ float siv;
    if (threadIdx.x < F) sm[threadIdx.x] = mean[threadIdx.x];
    if (threadIdx.x == 0) siv = invd[0];
    __syncthreads();
    float iv = siv;
    size_t total = (size_t)n * (F / 4);
    size_t i0 = (size_t)blockIdx.x * blockDim.x + threadIdx.x;
    size_t stride = (size_t)gridDim.x * blockDim.x;
    float4* o4 = (float4*)out;
    for (size_t i = i0; i < total; i += stride) {
        int c = (int)((i & 31) << 2);
        float4 v = o4[i];
        v.x = fmaxf(0.0f, (v.x - sm[c + 0]) * iv);
        v.y = fmaxf(0.0f, (v.y - sm[c + 1]) * iv);
        v.z = fmaxf(0.0f, (v.z - sm[c + 2]) * iv);
        v.w = fmaxf(0.0f, (v.w - sm[c + 3]) * iv);
        o4[i] = v;
    }
}

extern "C" void kernel_launch(void* const* d_in, const int* in_sizes, int n_in,
                              void* d_out, int out_size, void* d_ws, size_t ws_size,
                              hipStream_t stream) {
    const float* x    = (const float*)d_in[0];
    const int*   ei   = (const int*)d_in[1];   // [2, E] int32
    const float* ew   = (const float*)d_in[2];
    const float* W    = (const float*)d_in[3];
    const float* bias = (const float*)d_in[4];
    float* out = (float*)d_out;

    const int n = in_sizes[0] / F;
    const int E = in_sizes[2];
    const int* src = ei;
    const int* dst = ei + E;

    char* ws = (char*)d_ws;
    size_t off = 0;
    __hip_bfloat16* h = (__hip_bfloat16*)(ws + off); off += (size_t)n * F * sizeof(__hip_bfloat16);
    uint2* csr = (uint2*)(ws + off);                 off += (size_t)E * sizeof(uint2);
    unsigned long long* packed = (unsigned long long*)(ws + off); off += (size_t)n * 8;
    float* dis = (float*)(ws + off);      off += (size_t)n * sizeof(float);
    int* cnt = (int*)(ws + off);          off += (size_t)n * sizeof(int);
    int* row_start = (int*)(ws + off);    off += (size_t)n * sizeof(int);
    int* bsum = (int*)(ws + off);         off += 256 * sizeof(int);
    float* colsum = (float*)(ws + off);   off += F * sizeof(float);
    float* sumsq = (float*)(ws + off);    off += sizeof(float);
    float* mean = (float*)(ws + off);     off += F * sizeof(float);
    float* invd = (float*)(ws + off);     off += sizeof(float);
    unsigned short* rank = (unsigned short*)(ws + off); off += (size_t)E * sizeof(unsigned short);

    const int nb = (n + SCAN_CHUNK - 1) / SCAN_CHUNK;  // 98 for n=100000

    init_kernel<<<(n + 255) / 256, 256, 0, stream>>>(packed, colsum, sumsq, n);
    edge_hist<<<2048, 256, 0, stream>>>(dst, ew, packed, rank, E);
    unpack<<<(n + 255) / 256, 256, 0, stream>>>(packed, cnt, dis, n);
    scan_pass1<<<nb, 256, 0, stream>>>(cnt, bsum, n);
    scan_pass2<<<1, 256, 0, stream>>>(bsum, nb);
    scan_pass3<<<nb, 256, 0, stream>>>(cnt, bsum, row_start, n);
    scatter<<<2048, 256, 0, stream>>>(src, dst, ew, rank, dis, row_start, csr, E);
    gemm<<<(n + GR - 1) / GR, 128, 0, stream>>>(x, W, h, n);
    aggregate<<<(n * 16 + 255) / 256, 256, 0, stream>>>(
        (const uint4*)h, dis, bias, row_start, cnt, csr, (float4*)out, n);
    stats<<<2048, 256, 0, stream>>>(out, colsum, sumsq, n);
    reduce_stats<<<1, 128, 0, stream>>>(colsum, sumsq, mean, invd, n);
    finalize<<<2048, 256, 0, stream>>>(out, mean, invd, n);
}

// Round 4
// 307.503 us; speedup vs baseline: 9.7020x; 1.2369x over previous
//
#include <hip/hip_runtime.h>
#include <hip/hip_bf16.h>
#include <math.h>

#define F 128
#define PN_EPS 1e-5f
#define PN_SCALE 1.0f
#define GBM 64           // rows per block in MFMA GEMM
#define SCAN_CHUNK 1024  // elements per scan block (256 thr * 4)
#define FIX_SCALE 16777216.0f       // 2^24
#define FIX_INV   (1.0f / 16777216.0f)

using short8 = __attribute__((ext_vector_type(8))) short;
using f32x4  = __attribute__((ext_vector_type(4))) float;

__device__ __forceinline__ void atomic_add_f32(float* p, float v) {
#if defined(__AMDGCN__)
    unsafeAtomicAdd(p, v);
#else
    atomicAdd(p, v);
#endif
}

__device__ __forceinline__ unsigned short bf16_rne(float f) {
    union { float f; unsigned u; } v; v.f = f;
    unsigned r = v.u + 0x7fff + ((v.u >> 16) & 1);
    return (unsigned short)(r >> 16);
}

// K0: packed=0, zero stats accumulators
__global__ void init_kernel(unsigned long long* __restrict__ packed,
                            float* __restrict__ colsum, float* __restrict__ sumsq, int n) {
    int i = blockIdx.x * blockDim.x + threadIdx.x;
    if (i < n) packed[i] = 0ull;
    if (i < F) colsum[i] = 0.0f;
    if (i == F) sumsq[0] = 0.0f;
}

// W[k][col] f32 -> wt[col][k] bf16 (one-time transpose, 16K elems)
__global__ void wt_kernel(const float* __restrict__ W, unsigned short* __restrict__ wt) {
    int idx = blockIdx.x * blockDim.x + threadIdx.x;  // 0..16383
    int k = idx >> 7;
    int col = idx & 127;
    wt[col * F + k] = bf16_rne(W[idx]);
}

// K1: one u64 atomic per edge: packed[dst] += (1<<40) | fix24(w).
__global__ __launch_bounds__(256) void edge_hist(
    const int* __restrict__ dst, const float* __restrict__ ew,
    unsigned long long* __restrict__ packed, unsigned short* __restrict__ rank, int E) {
    int i = blockIdx.x * blockDim.x + threadIdx.x;
    int stride = gridDim.x * blockDim.x;
    for (int e = i; e < E; e += stride) {
        int d = dst[e];
        unsigned long long add =
            (1ull << 40) | (unsigned long long)__float2uint_rn(ew[e] * FIX_SCALE);
        unsigned long long old = atomicAdd(&packed[d], add);
        rank[e] = (unsigned short)(old >> 40);
    }
}

// K2: unpack -> cnt and dis = rsqrt(1 + sum_w)
__global__ void unpack(const unsigned long long* __restrict__ packed,
                       int* __restrict__ cnt, float* __restrict__ dis, int n) {
    int i = blockIdx.x * blockDim.x + threadIdx.x;
    if (i < n) {
        unsigned long long p = packed[i];
        cnt[i] = (int)(p >> 40);
        float deg = 1.0f + (float)(p & ((1ull << 40) - 1)) * FIX_INV;
        dis[i] = rsqrtf(deg);
    }
}

// --- 3-kernel exclusive scan of cnt[n] -> row_start[n] ---
__global__ __launch_bounds__(256) void scan_pass1(const int* __restrict__ cnt,
                                                  int* __restrict__ bsum, int n) {
    __shared__ int s[256];
    int base = blockIdx.x * SCAN_CHUNK + threadIdx.x * 4;
    int t = 0;
#pragma unroll
    for (int k = 0; k < 4; ++k)
        if (base + k < n) t += cnt[base + k];
    s[threadIdx.x] = t;
    __syncthreads();
    for (int off = 128; off >= 1; off >>= 1) {
        if (threadIdx.x < off) s[threadIdx.x] += s[threadIdx.x + off];
        __syncthreads();
    }
    if (threadIdx.x == 0) bsum[blockIdx.x] = s[0];
}

__global__ __launch_bounds__(256) void scan_pass2(int* __restrict__ bsum, int nb) {
    __shared__ int s[256];
    int t = threadIdx.x;
    int v = (t < nb) ? bsum[t] : 0;
    s[t] = v;
    __syncthreads();
    for (int off = 1; off < 256; off <<= 1) {
        int u = (t >= off) ? s[t - off] : 0;
        __syncthreads();
        s[t] += u;
        __syncthreads();
    }
    if (t < nb) bsum[t] = s[t] - v;  // exclusive
}

__global__ __launch_bounds__(256) void scan_pass3(const int* __restrict__ cnt,
                                                  const int* __restrict__ bsum,
                                                  int* __restrict__ row_start, int n) {
    __shared__ int s[256];
    int base = blockIdx.x * SCAN_CHUNK + threadIdx.x * 4;
    int c[4];
    int tot = 0;
#pragma unroll
    for (int k = 0; k < 4; ++k) {
        c[k] = (base + k < n) ? cnt[base + k] : 0;
        tot += c[k];
    }
    s[threadIdx.x] = tot;
    __syncthreads();
    for (int off = 1; off < 256; off <<= 1) {
        int u = (threadIdx.x >= off) ? s[threadIdx.x - off] : 0;
        __syncthreads();
        s[threadIdx.x] += u;
        __syncthreads();
    }
    int off = bsum[blockIdx.x] + s[threadIdx.x] - tot;
#pragma unroll
    for (int k = 0; k < 4; ++k) {
        if (base + k < n) {
            row_start[base + k] = off;
            off += c[k];
        }
    }
}

// K3: atomic-free scatter: csr[row_start[dst]+rank] = {src, norm}
__global__ __launch_bounds__(256) void scatter(const int* __restrict__ src,
                                               const int* __restrict__ dst,
                                               const float* __restrict__ ew,
                                               const unsigned short* __restrict__ rank,
                                               const float* __restrict__ dis,
                                               const int* __restrict__ row_start,
                                               uint2* __restrict__ csr, int E) {
    int i = blockIdx.x * blockDim.x + threadIdx.x;
    int stride = gridDim.x * blockDim.x;
    for (int e = i; e < E; e += stride) {
        int s = src[e];
        int d = dst[e];
        float nrm = dis[s] * ew[e] * dis[d];
        int pos = row_start[d] + (int)rank[e];
        csr[pos] = make_uint2((unsigned)s, __float_as_uint(nrm));
    }
}

// K4: h = x @ W via bf16 MFMA (16x16x32), bf16 output.
// Block: 256 thr = 4 waves; 64-row tile; wave w owns rows [w*16, w*16+16).
__global__ __launch_bounds__(256) void gemm_mfma(
    const float* __restrict__ x, const unsigned short* __restrict__ wt,  // wt[col][k] bf16
    unsigned short* __restrict__ h, int n) {
    __shared__ unsigned short xs[GBM][136];  // +8 pad: b128 reads 2 lanes/bank (free)
    const int row0 = blockIdx.x * GBM;

    // stage 64x128 f32 -> bf16 LDS (coalesced float4 loads)
#pragma unroll
    for (int i = 0; i < 8; ++i) {
        int idx = threadIdx.x + i * 256;  // float4 index, 0..2047
        int r = idx >> 5;
        int c4 = idx & 31;
        int rg = row0 + r;
        float4 v = (rg < n) ? ((const float4*)(x + (size_t)rg * F))[c4]
                            : make_float4(0.f, 0.f, 0.f, 0.f);
        uint2 p;
        p.x = (unsigned)bf16_rne(v.x) | ((unsigned)bf16_rne(v.y) << 16);
        p.y = (unsigned)bf16_rne(v.z) | ((unsigned)bf16_rne(v.w) << 16);
        *(uint2*)&xs[r][c4 * 4] = p;
    }
    __syncthreads();

    const int wid = threadIdx.x >> 6;   // wave 0..3
    const int lane = threadIdx.x & 63;
    const int l15 = lane & 15;
    const int kg = lane >> 4;           // 0..3
    const int wrow = wid * 16;

    // A frags: lane holds row (wrow+l15), k = s*32 + kg*8 .. +7 (contiguous)
    short8 afrag[4];
#pragma unroll
    for (int s = 0; s < 4; ++s)
        afrag[s] = *(const short8*)&xs[wrow + l15][s * 32 + kg * 8];

#pragma unroll
    for (int t = 0; t < 8; ++t) {
        // B frag: col = t*16 + l15, k = s*32 + kg*8 .. +7  -> contiguous in wt
        const unsigned short* wb = wt + (size_t)(t * 16 + l15) * F + kg * 8;
        short8 b0 = *(const short8*)(wb);
        short8 b1 = *(const short8*)(wb + 32);
        short8 b2 = *(const short8*)(wb + 64);
        short8 b3 = *(const short8*)(wb + 96);
        f32x4 acc = {0.f, 0.f, 0.f, 0.f};
        acc = __builtin_amdgcn_mfma_f32_16x16x32_bf16(afrag[0], b0, acc, 0, 0, 0);
        acc = __builtin_amdgcn_mfma_f32_16x16x32_bf16(afrag[1], b1, acc, 0, 0, 0);
        acc = __builtin_amdgcn_mfma_f32_16x16x32_bf16(afrag[2], b2, acc, 0, 0, 0);
        acc = __builtin_amdgcn_mfma_f32_16x16x32_bf16(afrag[3], b3, acc, 0, 0, 0);
        // C/D: col = lane&15, row = (lane>>4)*4 + reg   [m89/m91]
        int col = t * 16 + l15;
#pragma unroll
        for (int i = 0; i < 4; ++i) {
            int rg = row0 + wrow + kg * 4 + i;
            if (rg < n) h[(size_t)rg * F + col] = bf16_rne(acc[i]);
        }
    }
}

// K5: atomic-free aggregation, 16 lanes per dst node, bf16 h gathers.
__device__ __forceinline__ void bf16x8_fma(uint4 v, float m, float* acc) {
    union { uint4 u; unsigned short s[8]; } cv;
    cv.u = v;
#pragma unroll
    for (int j = 0; j < 8; ++j) {
        float f = __uint_as_float(((unsigned)cv.s[j]) << 16);
        acc[j] = fmaf(f, m, acc[j]);
    }
}

__global__ __launch_bounds__(256) void aggregate(
    const uint4* __restrict__ h16,   // node row = 16 chunks of 8 bf16
    const float* __restrict__ dis,
    const float* __restrict__ bias,
    const int* __restrict__ row_start, const int* __restrict__ cnt,
    const uint2* __restrict__ csr, float4* __restrict__ out4, int n) {
    int g = (blockIdx.x * blockDim.x + threadIdx.x) >> 4;
    int lane = threadIdx.x & 15;
    if (g >= n) return;

    float dv = dis[g];
    float sc = dv * dv;
    float4 b0 = ((const float4*)bias)[lane * 2];
    float4 b1 = ((const float4*)bias)[lane * 2 + 1];
    float acc[8] = {b0.x, b0.y, b0.z, b0.w, b1.x, b1.y, b1.z, b1.w};
    bf16x8_fma(h16[(size_t)g * 16 + lane], sc, acc);

    int e = row_start[g];
    const int e1 = e + cnt[g];
    for (; e + 1 < e1; e += 2) {
        uint2 r0 = csr[e];
        uint2 r1 = csr[e + 1];
        uint4 v0 = h16[(size_t)r0.x * 16 + lane];
        uint4 v1 = h16[(size_t)r1.x * 16 + lane];
        bf16x8_fma(v0, __uint_as_float(r0.y), acc);
        bf16x8_fma(v1, __uint_as_float(r1.y), acc);
    }
    if (e < e1) {
        uint2 r0 = csr[e];
        bf16x8_fma(h16[(size_t)r0.x * 16 + lane], __uint_as_float(r0.y), acc);
    }

    out4[(size_t)g * 32 + lane * 2]     = make_float4(acc[0], acc[1], acc[2], acc[3]);
    out4[(size_t)g * 32 + lane * 2 + 1] = make_float4(acc[4], acc[5], acc[6], acc[7]);
}

// K6: column sums + total sum of squares
__global__ __launch_bounds__(256) void stats(const float* __restrict__ agg,
                                             float* __restrict__ colsum,
                                             float* __restrict__ sumsq, int n) {
    const int col = threadIdx.x & (F - 1);
    const int plane = threadIdx.x >> 7;
    float cs = 0.0f, ss = 0.0f;
    for (int r = blockIdx.x * 2 + plane; r < n; r += gridDim.x * 2) {
        float v = agg[(size_t)r * F + col];
        cs += v;
        ss = fmaf(v, v, ss);
    }
    __shared__ float scs[256];
    scs[threadIdx.x] = cs;
    __syncthreads();
    if (threadIdx.x < F)
        atomic_add_f32(&colsum[threadIdx.x], scs[threadIdx.x] + scs[threadIdx.x + F]);

#pragma unroll
    for (int off = 32; off >= 1; off >>= 1) ss += __shfl_down(ss, off);
    __shared__ float sss[4];
    if ((threadIdx.x & 63) == 0) sss[threadIdx.x >> 6] = ss;
    __syncthreads();
    if (threadIdx.x == 0) atomic_add_f32(sumsq, sss[0] + sss[1] + sss[2] + sss[3]);
}

// K7: mean + inverse denom
__global__ void reduce_stats(const float* __restrict__ colsum, const float* __restrict__ sumsq,
                             float* __restrict__ mean, float* __restrict__ invd, int n) {
    int t = threadIdx.x;  // 128 threads
    float m = colsum[t] / (float)n;
    mean[t] = m;
    __shared__ float red[128];
    red[t] = m * m;
    __syncthreads();
    for (int off = 64; off >= 1; off >>= 1) {
        if (t < off) red[t] += red[t + off];
        __syncthreads();
    }
    if (t == 0) {
        float ssc = sumsq[0] - (float)n * red[0];
        if (ssc < 0.0f) ssc = 0.0f;
        float denom = sqrtf(PN_EPS + ssc / (float)n);
        invd[0] = PN_SCALE / denom;
    }
}

// K8: out = relu((out - mean) * invd)   in place
__global__ __launch_bounds__(256) void finalize(float* __restrict__ out,
                                                const float* __restrict__ mean,
                                                const float* __restrict__ invd, int n) {
    __shared__ float sm[F];
    __shared__ float siv;
    if (threadIdx.x < F) sm[threadIdx.x] = mean[threadIdx.x];
    if (threadIdx.x == 0) siv = invd[0];
    __syncthreads();
    float iv = siv;
    size_t total = (size_t)n * (F / 4);
    size_t i0 = (size_t)blockIdx.x * blockDim.x + threadIdx.x;
    size_t stride = (size_t)gridDim.x * blockDim.x;
    float4* o4 = (float4*)out;
    for (size_t i = i0; i < total; i += stride) {
        int c = (int)((i & 31) << 2);
        float4 v = o4[i];
        v.x = fmaxf(0.0f, (v.x - sm[c + 0]) * iv);
        v.y = fmaxf(0.0f, (v.y - sm[c + 1]) * iv);
        v.z = fmaxf(0.0f, (v.z - sm[c + 2]) * iv);
        v.w = fmaxf(0.0f, (v.w - sm[c + 3]) * iv);
        o4[i] = v;
    }
}

extern "C" void kernel_launch(void* const* d_in, const int* in_sizes, int n_in,
                              void* d_out, int out_size, void* d_ws, size_t ws_size,
                              hipStream_t stream) {
    const float* x    = (const float*)d_in[0];
    const int*   ei   = (const int*)d_in[1];   // [2, E] int32
    const float* ew   = (const float*)d_in[2];
    const float* W    = (const float*)d_in[3];
    const float* bias = (const float*)d_in[4];
    float* out = (float*)d_out;

    const int n = in_sizes[0] / F;
    const int E = in_sizes[2];
    const int* src = ei;
    const int* dst = ei + E;

    char* ws = (char*)d_ws;
    size_t off = 0;
    unsigned short* h = (unsigned short*)(ws + off); off += (size_t)n * F * sizeof(unsigned short);
    uint2* csr = (uint2*)(ws + off);                 off += (size_t)E * sizeof(uint2);
    unsigned long long* packed = (unsigned long long*)(ws + off); off += (size_t)n * 8;
    float* dis = (float*)(ws + off);      off += (size_t)n * sizeof(float);
    int* cnt = (int*)(ws + off);          off += (size_t)n * sizeof(int);
    int* row_start = (int*)(ws + off);    off += (size_t)n * sizeof(int);
    int* bsum = (int*)(ws + off);         off += 256 * sizeof(int);
    float* colsum = (float*)(ws + off);   off += F * sizeof(float);
    float* sumsq = (float*)(ws + off);    off += sizeof(float);
    float* mean = (float*)(ws + off);     off += F * sizeof(float);
    float* invd = (float*)(ws + off);     off += sizeof(float);
    unsigned short* rank = (unsigned short*)(ws + off); off += (size_t)E * sizeof(unsigned short);
    unsigned short* wt = (unsigned short*)(ws + off);   off += (size_t)F * F * sizeof(unsigned short);

    const int nb = (n + SCAN_CHUNK - 1) / SCAN_CHUNK;  // 98 for n=100000

    init_kernel<<<(n + 255) / 256, 256, 0, stream>>>(packed, colsum, sumsq, n);
    wt_kernel<<<64, 256, 0, stream>>>(W, wt);
    edge_hist<<<2048, 256, 0, stream>>>(dst, ew, packed, rank, E);
    unpack<<<(n + 255) / 256, 256, 0, stream>>>(packed, cnt, dis, n);
    scan_pass1<<<nb, 256, 0, stream>>>(cnt, bsum, n);
    scan_pass2<<<1, 256, 0, stream>>>(bsum, nb);
    scan_pass3<<<nb, 256, 0, stream>>>(cnt, bsum, row_start, n);
    scatter<<<2048, 256, 0, stream>>>(src, dst, ew, rank, dis, row_start, csr, E);
    gemm_mfma<<<(n + GBM - 1) / GBM, 256, 0, stream>>>(x, wt, h, n);
    aggregate<<<(n * 16 + 255) / 256, 256, 0, stream>>>(
        (const uint4*)h, dis, bias, row_start, cnt, csr, (float4*)out, n);
    stats<<<2048, 256, 0, stream>>>(out, colsum, sumsq, n);
    reduce_stats<<<1, 128, 0, stream>>>(colsum, sumsq, mean, invd, n);
    finalize<<<2048, 256, 0, stream>>>(out, mean, invd, n);
}